// Round 2
// baseline (457.389 us; speedup 1.0000x reference)
//
#include <hip/hip_runtime.h>

#define NROWS 262144
#define NCOLS 128
#define TPB 256
#define WPB (TPB / 64)
#define NBLOCKS 4096
#define NWAVES (NBLOCKS * WPB)           // 16384 waves
#define NPAIRS (NROWS / 2)               // 131072
#define U 2                              // pairs batched per load phase
#define NBATCH (NPAIRS / (NWAVES * U))   // 4 batches per wave

typedef float floatx4 __attribute__((ext_vector_type(4)));

__device__ __forceinline__ floatx4 ntload4(const float* p)
{
    return __builtin_nontemporal_load((const floatx4*)p);
}

// Lanes 0-31 -> row 2p, lanes 32-63 -> row 2p+1; each lane loads one float4
// of x and t (wave covers 1KB contiguous per array per pair). Non-temporal:
// streams past L2/L3 so we don't evict the harness's restore data.
//
// R2 changes (both bit-identical to the R1 reduction tree):
//  1. Ballot-based argmax: we never need the index itself, only
//     (argmax>0) <=> (x[row][0] != M) and t[argmax] (from the first lane
//     whose 4 columns contain M). 11 shuffles/pair -> 7 shuffles + 1 ballot.
//     The contributing lane and its value fabsf(M)*t (== fabsf(M*t), t
//     binary) are the same lane/value as before -> wave sums bit-identical.
//  2. Fused final reduction via last-block-done (atomicAdd counter +
//     threadfence), eliminating the reduce_partials launch. The last block
//     runs the exact same stride-256 / butterfly / 4-way smem sum as the
//     old second kernel -> bit-identical output.
__global__ __launch_bounds__(TPB) void biased_loss_fused(
    const float* __restrict__ x, const float* __restrict__ t,
    float* __restrict__ partial, unsigned int* __restrict__ counter,
    float* __restrict__ out)
{
    const int lane = threadIdx.x & 63;
    const int waveInBlock = threadIdx.x >> 6;
    const int gw = blockIdx.x * WPB + waveInBlock;
    const int half = lane >> 5;
    const int sub  = lane & 31;
    const int c    = sub * 4;

    const size_t laneoff = (size_t)half * NCOLS + (size_t)c;

    float acc = 0.0f;

    floatx4 xv[U], tv[U];   // current batch
    floatx4 xn[U], tn[U];   // prefetched next batch

    // prologue: issue batch 0's loads
    {
        const int pbase = gw * U;
        #pragma unroll
        for (int u = 0; u < U; ++u) {
            const size_t base = (size_t)(2 * (pbase + u)) * NCOLS + laneoff;
            xv[u] = ntload4(x + base);
            tv[u] = ntload4(t + base);
        }
    }

    #pragma unroll
    for (int b = 0; b < NBATCH; ++b) {
        // issue batch b+1's loads before consuming batch b
        if (b + 1 < NBATCH) {
            const int pbase = ((b + 1) * NWAVES + gw) * U;
            #pragma unroll
            for (int u = 0; u < U; ++u) {
                const size_t base = (size_t)(2 * (pbase + u)) * NCOLS + laneoff;
                xn[u] = ntload4(x + base);
                tn[u] = ntload4(t + base);
            }
        }

        #pragma unroll
        for (int u = 0; u < U; ++u) {
            // lane-local max of this lane's 4 columns (value only)
            const float lm = fmaxf(fmaxf(xv[u].x, xv[u].y),
                                   fmaxf(xv[u].z, xv[u].w));

            // butterfly max across the 32-lane half -> M in every lane
            float M = lm;
            #pragma unroll
            for (int off = 16; off > 0; off >>= 1)
                M = fmaxf(M, __shfl_xor(M, off, 64));

            // t at the first column of THIS lane achieving M (garbage unless
            // this lane holds a match)
            const float tb_local = (xv[u].x == M) ? tv[u].x :
                                   (xv[u].y == M) ? tv[u].y :
                                   (xv[u].z == M) ? tv[u].z : tv[u].w;

            // first lane within this half whose columns contain M == the lane
            // that held bi (first occurrence) in the old index butterfly
            const unsigned long long mask = __ballot(lm == M);
            const unsigned int mh = (unsigned int)(mask >> (half << 5));
            const int L = (half << 5) + (__ffs(mh) - 1);

            const float x0 = __shfl(xv[u].x, half << 5, 64);
            const float t0 = __shfl(tv[u].x, half << 5, 64);
            // argmax>0 <=> first occurrence of M is not column 0 <=> x0 != M
            const bool cond = (x0 != M) && (t0 == 0.0f);

            float s;
            if (cond) {
                // only the first-matching lane contributes, same lane and same
                // bits as the old (c+j==bi ? cj : 0) sum: fabs(M*t)==fabs(M)*t
                s = (lane == L) ? fabsf(M) * tb_local : 0.0f;
            } else {
                const float c0 = fabsf(xv[u].x * tv[u].x);
                const float c1 = fabsf(xv[u].y * tv[u].y);
                const float c2 = fabsf(xv[u].z * tv[u].z);
                const float c3 = fabsf(xv[u].w * tv[u].w);
                s = (c0 + c1) + (c2 + c3);
            }
            acc += s;
        }

        if (b + 1 < NBATCH) {
            #pragma unroll
            for (int u = 0; u < U; ++u) { xv[u] = xn[u]; tv[u] = tn[u]; }
        }
    }

    // full-wave sum
    #pragma unroll
    for (int off = 32; off > 0; off >>= 1)
        acc += __shfl_xor(acc, off, 64);

    __shared__ float smem[WPB];
    __shared__ int isLast;
    if (lane == 0) smem[waveInBlock] = acc;
    __syncthreads();
    if (threadIdx.x == 0) {
        float bsum = 0.0f;
        #pragma unroll
        for (int w = 0; w < WPB; ++w) bsum += smem[w];
        partial[blockIdx.x] = bsum;
        __threadfence();                       // publish partial before ticket
        const unsigned int prev = atomicAdd(counter, 1u);
        isLast = (prev == NBLOCKS - 1);
    }
    __syncthreads();

    if (isLast) {
        __threadfence();                       // acquire all partial[] stores
        // exact replica of the old reduce_partials kernel
        float r = 0.0f;
        for (int i = threadIdx.x; i < NBLOCKS; i += TPB) r += partial[i];
        #pragma unroll
        for (int off = 32; off > 0; off >>= 1)
            r += __shfl_xor(r, off, 64);
        __shared__ float smem2[WPB];
        if (lane == 0) smem2[waveInBlock] = r;
        __syncthreads();
        if (threadIdx.x == 0) {
            const float s2 = smem2[0] + smem2[1] + smem2[2] + smem2[3];
            out[0] = s2 / (float)((size_t)NROWS * (size_t)NCOLS);
        }
    }
}

extern "C" void kernel_launch(void* const* d_in, const int* in_sizes, int n_in,
                              void* d_out, int out_size, void* d_ws, size_t ws_size,
                              hipStream_t stream) {
    const float* x = (const float*)d_in[0];
    const float* t = (const float*)d_in[1];
    float* partial = (float*)d_ws;                      // NBLOCKS * 4 B
    unsigned int* counter = (unsigned int*)(partial + NBLOCKS);

    // zero the last-block ticket (workspace is re-poisoned every iteration);
    // memset node is graph-capture-legal (harness reset uses the same op)
    hipMemsetAsync((void*)counter, 0, sizeof(unsigned int), stream);
    biased_loss_fused<<<NBLOCKS, TPB, 0, stream>>>(x, t, partial, counter,
                                                   (float*)d_out);
}

// Round 3
// 277.173 us; speedup vs baseline: 1.6502x; 1.6502x over previous
//
#include <hip/hip_runtime.h>

#define NROWS 262144
#define NCOLS 128
#define TPB 256
#define WPB (TPB / 64)
#define NBLOCKS 4096
#define NWAVES (NBLOCKS * WPB)           // 16384 waves
#define NPAIRS (NROWS / 2)               // 131072
#define U 2                              // pairs batched per load phase
#define NBATCH (NPAIRS / (NWAVES * U))   // 4 batches per wave

typedef float floatx4 __attribute__((ext_vector_type(4)));

__device__ __forceinline__ floatx4 load4(const float* p)
{
    // R3: plain (allocating) loads. NT was never A/B'd; m13's 6.29 TB/s read
    // ceiling used plain float4 loads, and the freshly-restored t array is
    // sitting in L2 from the harness copy — nt forfeits those hits.
    return *(const floatx4*)p;
}

// Lanes 0-31 -> row 2p, lanes 32-63 -> row 2p+1; each lane loads one float4
// of x and t (wave covers 1KB contiguous per array per pair).
//
// R3 = R1 two-kernel structure (the R2 fused epilogue cost ~165us in
// cross-XCD threadfence/atomic serialization -- reverted) + the R2 ballot
// argmax (proven bit-exact in R2, absmax 0.0) + plain instead of nt loads.
__global__ __launch_bounds__(TPB) void biased_loss_partial(
    const float* __restrict__ x, const float* __restrict__ t,
    float* __restrict__ partial)
{
    const int lane = threadIdx.x & 63;
    const int waveInBlock = threadIdx.x >> 6;
    const int gw = blockIdx.x * WPB + waveInBlock;
    const int half = lane >> 5;
    const int sub  = lane & 31;
    const int c    = sub * 4;

    const size_t laneoff = (size_t)half * NCOLS + (size_t)c;

    float acc = 0.0f;

    floatx4 xv[U], tv[U];   // current batch
    floatx4 xn[U], tn[U];   // prefetched next batch

    // prologue: issue batch 0's loads
    {
        const int pbase = gw * U;
        #pragma unroll
        for (int u = 0; u < U; ++u) {
            const size_t base = (size_t)(2 * (pbase + u)) * NCOLS + laneoff;
            xv[u] = load4(x + base);
            tv[u] = load4(t + base);
        }
    }

    #pragma unroll
    for (int b = 0; b < NBATCH; ++b) {
        // issue batch b+1's loads before consuming batch b
        if (b + 1 < NBATCH) {
            const int pbase = ((b + 1) * NWAVES + gw) * U;
            #pragma unroll
            for (int u = 0; u < U; ++u) {
                const size_t base = (size_t)(2 * (pbase + u)) * NCOLS + laneoff;
                xn[u] = load4(x + base);
                tn[u] = load4(t + base);
            }
        }

        #pragma unroll
        for (int u = 0; u < U; ++u) {
            // lane-local max of this lane's 4 columns (value only)
            const float lm = fmaxf(fmaxf(xv[u].x, xv[u].y),
                                   fmaxf(xv[u].z, xv[u].w));

            // butterfly max across the 32-lane half -> M in every lane
            float M = lm;
            #pragma unroll
            for (int off = 16; off > 0; off >>= 1)
                M = fmaxf(M, __shfl_xor(M, off, 64));

            // t at the first column of THIS lane achieving M (garbage unless
            // this lane holds a match)
            const float tb_local = (xv[u].x == M) ? tv[u].x :
                                   (xv[u].y == M) ? tv[u].y :
                                   (xv[u].z == M) ? tv[u].z : tv[u].w;

            // first lane within this half whose columns contain M == the lane
            // that held the first-occurrence argmax
            const unsigned long long mask = __ballot(lm == M);
            const unsigned int mh = (unsigned int)(mask >> (half << 5));
            const int L = (half << 5) + (__ffs(mh) - 1);

            const float x0 = __shfl(xv[u].x, half << 5, 64);
            const float t0 = __shfl(tv[u].x, half << 5, 64);
            // argmax>0 <=> first occurrence of M is not column 0 <=> x0 != M
            const bool cond = (x0 != M) && (t0 == 0.0f);

            float s;
            if (cond) {
                // only the first-matching lane contributes; fabs(M)*t ==
                // fabs(M*t) bit-exactly (t is 0.0 or 1.0, signs preserved)
                s = (lane == L) ? fabsf(M) * tb_local : 0.0f;
            } else {
                const float c0 = fabsf(xv[u].x * tv[u].x);
                const float c1 = fabsf(xv[u].y * tv[u].y);
                const float c2 = fabsf(xv[u].z * tv[u].z);
                const float c3 = fabsf(xv[u].w * tv[u].w);
                s = (c0 + c1) + (c2 + c3);
            }
            acc += s;
        }

        if (b + 1 < NBATCH) {
            #pragma unroll
            for (int u = 0; u < U; ++u) { xv[u] = xn[u]; tv[u] = tn[u]; }
        }
    }

    // full-wave sum
    #pragma unroll
    for (int off = 32; off > 0; off >>= 1)
        acc += __shfl_xor(acc, off, 64);

    __shared__ float smem[WPB];
    if (lane == 0) smem[waveInBlock] = acc;
    __syncthreads();
    if (threadIdx.x == 0) {
        float bsum = 0.0f;
        #pragma unroll
        for (int w = 0; w < WPB; ++w) bsum += smem[w];
        partial[blockIdx.x] = bsum;
    }
}

__global__ __launch_bounds__(256) void reduce_partials(
    const float* __restrict__ partial, float* __restrict__ out, int n)
{
    float acc = 0.0f;
    for (int i = threadIdx.x; i < n; i += 256) acc += partial[i];
    #pragma unroll
    for (int off = 32; off > 0; off >>= 1)
        acc += __shfl_xor(acc, off, 64);
    __shared__ float smem[4];
    const int lane = threadIdx.x & 63, w = threadIdx.x >> 6;
    if (lane == 0) smem[w] = acc;
    __syncthreads();
    if (threadIdx.x == 0) {
        float s = smem[0] + smem[1] + smem[2] + smem[3];
        out[0] = s / (float)((size_t)NROWS * (size_t)NCOLS);
    }
}

extern "C" void kernel_launch(void* const* d_in, const int* in_sizes, int n_in,
                              void* d_out, int out_size, void* d_ws, size_t ws_size,
                              hipStream_t stream) {
    const float* x = (const float*)d_in[0];
    const float* t = (const float*)d_in[1];
    float* partial = (float*)d_ws;  // NBLOCKS * 4 B = 16 KiB scratch

    biased_loss_partial<<<NBLOCKS, TPB, 0, stream>>>(x, t, partial);
    reduce_partials<<<1, 256, 0, stream>>>(partial, (float*)d_out, NBLOCKS);
}